// Round 19
// baseline (150.871 us; speedup 1.0000x reference)
//

#include <hip/hip_runtime.h>

// RadiusInteractionGraph: B=128 molecules x 512 atoms, K=32 NN, cutoff 10.
// d_out is FLOAT32: [E] src ++ [E] dst ++ [E] weight, E = 128*512*32.
//
// R19: replace R15's 32-round wave-min extraction (~930 VALU/row) with a
// rank-select: keys are UNIQUE (low 9 bits = j), so the 32nd-smallest key X
// is built MSB-first in 31 wave-uniform steps using ballot counts
// (8 v_cmp/step; bcnt/adds ride the scalar pipe). {k <= X} is then exactly
// the 32 smallest; scatter via ballot+mbcnt (no atomics), bitonic-sort 32
// across lanes, emit. Sentinel = 0x7F800000|j (unique, after all valid keys,
// decodes to self-edge) keeps <32-valid rows exact. Output bit-identical to
// R15 (same 23-bit-quantized lex order == lax.top_k stable order; exact
// __f*_rn np arithmetic).
// R18 lesson: keep hot cross-lane work off the contended LDS pipe — this
// design uses ~24 LDS ops/row (vs R18's 72) and no LDS in the select loop.

constexpr int EDGES = 128 * 512 * 32;   // 2097152

static __device__ __forceinline__ unsigned umin2(unsigned a, unsigned b) {
    return a < b ? a : b;
}
static __device__ __forceinline__ unsigned umax2(unsigned a, unsigned b) {
    return a > b ? a : b;
}

// #lanes below me with bit set in 64-bit mask
static __device__ __forceinline__ unsigned mbcnt64(unsigned long long m) {
    return __builtin_amdgcn_mbcnt_hi(
        (unsigned)(m >> 32),
        __builtin_amdgcn_mbcnt_lo((unsigned)m, 0u));
}

__global__ __launch_bounds__(256)
void RadiusInteractionGraph_73246372266582_kernel(const float* __restrict__ pos,
                                                  float* __restrict__ out) {
    __shared__ float4 atoms[512];       // x, y, z, |p|^2
    __shared__ unsigned wbuf[4][32];    // per-wave selected-key buffer

    const int tid     = threadIdx.x;
    const int b       = blockIdx.x >> 5;          // 32 blocks per molecule
    const int rowbase = (blockIdx.x & 31) * 16;   // 16 rows per block
    const int base    = b * 512;

    for (int a = tid; a < 512; a += 256) {
        float x = pos[(base + a) * 3 + 0];
        float y = pos[(base + a) * 3 + 1];
        float z = pos[(base + a) * 3 + 2];
        // np: sum(p*p) = (x*x + y*y) + z*z, sequential f32, no fma
        float sq = __fadd_rn(__fadd_rn(__fmul_rn(x, x), __fmul_rn(y, y)),
                             __fmul_rn(z, z));
        atoms[a] = make_float4(x, y, z, sq);
    }
    __syncthreads();

    const int wave = tid >> 6;
    const int lane = tid & 63;
    const int l5   = lane & 31;

    for (int rr = 0; rr < 4; ++rr) {
        const int i = rowbase + wave * 4 + rr;    // this wave's center row
        const float4 ci = atoms[i];               // uniform addr -> broadcast

        // ---- build 8 UNIQUE candidate keys per lane (j = c*64 + lane) ----
        unsigned q[8];
#pragma unroll
        for (int c = 0; c < 8; ++c) {
            const int j = c * 64 + lane;
            const float4 pj = atoms[j];           // one ds_read_b128
            // np einsum order: ((xi*xj + yi*yj) + zi*zj), plain f32, no fma
            float dot = __fadd_rn(__fadd_rn(__fmul_rn(ci.x, pj.x),
                                            __fmul_rn(ci.y, pj.y)),
                                  __fmul_rn(ci.z, pj.z));
            float d2 = __fsub_rn(__fadd_rn(ci.w, pj.w), __fmul_rn(2.0f, dot));
            d2 = fmaxf(d2, 0.0f);
            q[c] = ((j != i) && (d2 <= 100.0f))
                       ? ((__float_as_uint(d2) & 0xFFFFFE00u) | (unsigned)j)
                       : (0x7F800000u | (unsigned)j);   // sentinel, unique
        }
        // all keys < 2^31 -> search bits 30..0

        // ---- X = 32nd smallest key, MSB-first construction (wave-uniform) ----
        unsigned X = 0u;
        for (int bit = 30; bit >= 0; --bit) {
            const unsigned C = X | (1u << bit);
            unsigned cnt = 0;
#pragma unroll
            for (int c = 0; c < 8; ++c)
                cnt += (unsigned)__popcll(__ballot(q[c] < C));
            if (cnt < 32u) X = C;    // s_cselect; keeps cnt(<X) <= 31
        }
        // selected = { key <= X }: exactly 32 keys (keys unique).

        // ---- scatter selected keys to wbuf (ballot+mbcnt, no atomics) ----
        unsigned totals = 0;
#pragma unroll
        for (int c = 0; c < 8; ++c) {
            const bool sel = (q[c] <= X);
            const unsigned long long m = __ballot(sel);
            const unsigned off = totals + mbcnt64(m);
            if (sel) wbuf[wave][off] = q[c];      // off < 32 guaranteed
            totals += (unsigned)__popcll(m);
        }

        // per-wave LDS ops are in-order: writes above complete before this read
        unsigned v = wbuf[wave][l5];   // lanes 32..63 mirror 0..31 (discarded)

        // ---- bitonic sort 32 ascending across lanes 0..31 ----
#pragma unroll
        for (int k = 2; k <= 32; k <<= 1) {
#pragma unroll
            for (int j = k >> 1; j > 0; j >>= 1) {
                const unsigned p = (unsigned)__shfl_xor((int)v, j, 64);
                const bool keepmin = (((l5 & j) == 0) == ((l5 & k) == 0));
                const unsigned mn = umin2(v, p);
                const unsigned mx = umax2(v, p);
                v = keepmin ? mn : mx;
            }
        }

        // ---- epilogue: lanes 0..31 -> coalesced 128 B stores per region ----
        if (lane < 32) {
            const int gdst = base + i;
            float w = 0.0f;
            float srcf = (float)gdst;             // sentinel -> self-edge, w=0
            if (v < 0x7F800000u) {
                const int j = (int)(v & 511u);
                const float4 pj = atoms[j];
                float dot = __fadd_rn(__fadd_rn(__fmul_rn(ci.x, pj.x),
                                                __fmul_rn(ci.y, pj.y)),
                                      __fmul_rn(ci.z, pj.z));
                float d2 = __fsub_rn(__fadd_rn(ci.w, pj.w),
                                     __fmul_rn(2.0f, dot));
                d2 = fmaxf(d2, 0.0f);
                w = __fsqrt_rn(fmaxf(d2, 1e-12f));
                srcf = (float)(base + j);
            }
            const size_t eb = (size_t)gdst * 32 + (size_t)lane;
            out[eb]                     = srcf;          // src
            out[(size_t)EDGES + eb]     = (float)gdst;   // dst
            out[(size_t)EDGES * 2 + eb] = w;             // weight
        }
    }
}

extern "C" void kernel_launch(void* const* d_in, const int* in_sizes, int n_in,
                              void* d_out, int out_size, void* d_ws, size_t ws_size,
                              hipStream_t stream) {
    (void)in_sizes; (void)n_in; (void)d_ws; (void)ws_size; (void)out_size;
    const float* pos = (const float*)d_in[0];   // [N,3] f32
    float* out       = (float*)d_out;           // [3E] f32

    RadiusInteractionGraph_73246372266582_kernel<<<dim3(4096), dim3(256), 0,
                                                   stream>>>(pos, out);
}


// Round 20
// 110.145 us; speedup vs baseline: 1.3697x; 1.3697x over previous
//

#include <hip/hip_runtime.h>

// RadiusInteractionGraph: B=128 molecules x 512 atoms, K=32 NN, cutoff 10.
// d_out is FLOAT32: [E] src ++ [E] dst ++ [E] weight, E = 128*512*32.
//
// R20: truncated rank-select. R19's 31-iteration bit loop was SALU-bound
// (~560 SALU/row on the one scalar unit per CU -> 60us floor, VALUBusy 50%).
// Here the loop runs only bits 30..21 (10 iters) to get a pruning window
// {key < X + 2^21} containing the top-32 (typically ~33 keys). Compact the
// window (ballot+mbcnt, sentinel-padded to 64), bitonic-sort-64 across the
// wave, lanes 0..31 = exact ordered top-32. Fallback (W > 64, ~never on
// N(0,3) data): continue the loop to bit 0 — exact R19 path, so correctness
// is unconditional. Per-lane sort-8 deleted (not needed by this scheme).
// Output bit-identical to R15/R19: key = (d2_hi23 | j) lexicographic ==
// lax.top_k stable order; exact __f*_rn np arithmetic; sentinel keys
// 0x7F800000|j decode to pad self-edges.

constexpr int EDGES = 128 * 512 * 32;   // 2097152

static __device__ __forceinline__ unsigned umin2(unsigned a, unsigned b) {
    return a < b ? a : b;
}
static __device__ __forceinline__ unsigned umax2(unsigned a, unsigned b) {
    return a > b ? a : b;
}

// #lanes below me with bit set in 64-bit mask
static __device__ __forceinline__ unsigned mbcnt64(unsigned long long m) {
    return __builtin_amdgcn_mbcnt_hi(
        (unsigned)(m >> 32),
        __builtin_amdgcn_mbcnt_lo((unsigned)m, 0u));
}

// wave-wide count of keys < C (8 ballots; popc/add ride the scalar pipe)
static __device__ __forceinline__ unsigned count_lt(const unsigned q[8],
                                                    unsigned C) {
    unsigned cnt = 0;
#pragma unroll
    for (int c = 0; c < 8; ++c)
        cnt += (unsigned)__popcll(__ballot(q[c] < C));
    return cnt;
}

__global__ __launch_bounds__(256)
void RadiusInteractionGraph_73246372266582_kernel(const float* __restrict__ pos,
                                                  float* __restrict__ out) {
    __shared__ float4 atoms[512];       // x, y, z, |p|^2
    __shared__ unsigned wbuf[4][64];    // per-wave window buffer

    const int tid     = threadIdx.x;
    const int b       = blockIdx.x >> 5;          // 32 blocks per molecule
    const int rowbase = (blockIdx.x & 31) * 16;   // 16 rows per block
    const int base    = b * 512;

    for (int a = tid; a < 512; a += 256) {
        float x = pos[(base + a) * 3 + 0];
        float y = pos[(base + a) * 3 + 1];
        float z = pos[(base + a) * 3 + 2];
        // np: sum(p*p) = (x*x + y*y) + z*z, sequential f32, no fma
        float sq = __fadd_rn(__fadd_rn(__fmul_rn(x, x), __fmul_rn(y, y)),
                             __fmul_rn(z, z));
        atoms[a] = make_float4(x, y, z, sq);
    }
    __syncthreads();

    const int wave = tid >> 6;
    const int lane = tid & 63;

    for (int rr = 0; rr < 4; ++rr) {
        const int i = rowbase + wave * 4 + rr;    // this wave's center row
        const float4 ci = atoms[i];               // uniform addr -> broadcast

        // ---- build 8 UNIQUE candidate keys per lane (j = c*64 + lane) ----
        unsigned q[8];
#pragma unroll
        for (int c = 0; c < 8; ++c) {
            const int j = c * 64 + lane;
            const float4 pj = atoms[j];           // one ds_read_b128
            // np einsum order: ((xi*xj + yi*yj) + zi*zj), plain f32, no fma
            float dot = __fadd_rn(__fadd_rn(__fmul_rn(ci.x, pj.x),
                                            __fmul_rn(ci.y, pj.y)),
                                  __fmul_rn(ci.z, pj.z));
            float d2 = __fsub_rn(__fadd_rn(ci.w, pj.w), __fmul_rn(2.0f, dot));
            d2 = fmaxf(d2, 0.0f);
            q[c] = ((j != i) && (d2 <= 100.0f))
                       ? ((__float_as_uint(d2) & 0xFFFFFE00u) | (unsigned)j)
                       : (0x7F800000u | (unsigned)j);   // sentinel, unique
        }
        // all keys < 2^31

        // ---- truncated greedy MSB rank bound: bits 30..21 (10 iters) ----
        unsigned X = 0u;
        for (int bit = 30; bit >= 21; --bit) {
            const unsigned C = X | (1u << bit);
            if (count_lt(q, C) < 32u) X = C;      // keep cnt(<X) < 32
        }
        unsigned hi = X + (1u << 21);             // window: cnt(<hi) >= 32
        unsigned W = count_lt(q, hi);
        if (W > 64u) {
            // pathological ties: refine exactly (R19 path). After this,
            // X = 32nd-smallest key; window {<= X} has exactly 32 keys.
            for (int bit = 20; bit >= 0; --bit) {
                const unsigned C = X | (1u << bit);
                if (count_lt(q, C) < 32u) X = C;
            }
            hi = X + 1u;
        }

        // ---- compact window keys to wbuf; sentinel-pad to 64 ----
        wbuf[wave][lane] = 0xFFFFFFFFu;           // per-wave LDS is in-order
        unsigned totals = 0;
#pragma unroll
        for (int c = 0; c < 8; ++c) {
            const bool sel = (q[c] < hi);
            const unsigned long long m = __ballot(sel);
            const unsigned off = totals + mbcnt64(m);
            if (sel) wbuf[wave][off] = q[c];      // off < 64 guaranteed
            totals += (unsigned)__popcll(m);
        }

        unsigned v = wbuf[wave][lane];

        // ---- bitonic sort 64 ascending across the wave (R19 formula) ----
#pragma unroll
        for (int k = 2; k <= 64; k <<= 1) {
#pragma unroll
            for (int j = k >> 1; j > 0; j >>= 1) {
                const unsigned p = (unsigned)__shfl_xor((int)v, j, 64);
                const bool keepmin = (((lane & j) == 0) == ((lane & k) == 0));
                const unsigned mn = umin2(v, p);
                const unsigned mx = umax2(v, p);
                v = keepmin ? mn : mx;
            }
        }
        // lanes 0..31 now hold the exact ordered top-32 (W >= 32 always,
        // so no 0xFFFFFFFF padding lands in the first 32).

        // ---- epilogue: lanes 0..31 -> coalesced 128 B stores per region ----
        if (lane < 32) {
            const int gdst = base + i;
            float w = 0.0f;
            float srcf = (float)gdst;             // sentinel -> self-edge, w=0
            if (v < 0x7F800000u) {
                const int j = (int)(v & 511u);
                const float4 pj = atoms[j];
                float dot = __fadd_rn(__fadd_rn(__fmul_rn(ci.x, pj.x),
                                                __fmul_rn(ci.y, pj.y)),
                                      __fmul_rn(ci.z, pj.z));
                float d2 = __fsub_rn(__fadd_rn(ci.w, pj.w),
                                     __fmul_rn(2.0f, dot));
                d2 = fmaxf(d2, 0.0f);
                w = __fsqrt_rn(fmaxf(d2, 1e-12f));
                srcf = (float)(base + j);
            }
            const size_t eb = (size_t)gdst * 32 + (size_t)lane;
            out[eb]                     = srcf;          // src
            out[(size_t)EDGES + eb]     = (float)gdst;   // dst
            out[(size_t)EDGES * 2 + eb] = w;             // weight
        }
    }
}

extern "C" void kernel_launch(void* const* d_in, const int* in_sizes, int n_in,
                              void* d_out, int out_size, void* d_ws, size_t ws_size,
                              hipStream_t stream) {
    (void)in_sizes; (void)n_in; (void)d_ws; (void)ws_size; (void)out_size;
    const float* pos = (const float*)d_in[0];   // [N,3] f32
    float* out       = (float*)d_out;           // [3E] f32

    RadiusInteractionGraph_73246372266582_kernel<<<dim3(4096), dim3(256), 0,
                                                   stream>>>(pos, out);
}


// Round 21
// 102.292 us; speedup vs baseline: 1.4749x; 1.0768x over previous
//

#include <hip/hip_runtime.h>

// RadiusInteractionGraph: B=128 molecules x 512 atoms, K=32 NN, cutoff 10.
// d_out is FLOAT32: [E] src ++ [E] dst ++ [E] weight, E = 128*512*32.
//
// R21 = R20 truncated rank-select (PASS @ 57us kernel) + dual-row interleave.
// R20's counters (VALUBusy 58%, no pipe saturated) show a dependency-latency
// regime: the bit loop is a serial VALU->SALU->VALU chain, the sort a serial
// shfl chain. Two independent rows interleaved per wave fill each other's
// stall slots (R17 proved interleave useless when issue-bound at 98% — this
// is the latency-bound counterpart where it should pay). Bitonic strides 1,2
// via DPP quad_perm (exact xor partners, VALU pipe) trim LDS-pipe latency.
// Selection semantics bit-identical: key=(d2_hi23|j) lex == lax.top_k stable
// order; exact __f*_rn np arithmetic; sentinel 0x7F800000|j -> pad self-edge;
// W>64 fallback refines exactly (unconditional correctness).

constexpr int EDGES = 128 * 512 * 32;   // 2097152

static __device__ __forceinline__ unsigned umin2(unsigned a, unsigned b) {
    return a < b ? a : b;
}
static __device__ __forceinline__ unsigned umax2(unsigned a, unsigned b) {
    return a > b ? a : b;
}

static __device__ __forceinline__ unsigned mbcnt64(unsigned long long m) {
    return __builtin_amdgcn_mbcnt_hi(
        (unsigned)(m >> 32),
        __builtin_amdgcn_mbcnt_lo((unsigned)m, 0u));
}

static __device__ __forceinline__ unsigned count_lt(const unsigned q[8],
                                                    unsigned C) {
    unsigned cnt = 0;
#pragma unroll
    for (int c = 0; c < 8; ++c)
        cnt += (unsigned)__popcll(__ballot(q[c] < C));
    return cnt;
}

// xor-partner fetch: strides 1,2 via DPP quad_perm (VALU); 4..32 via shfl.
template <int J>
static __device__ __forceinline__ unsigned xpart(unsigned v) {
    if (J == 1) {
        return (unsigned)__builtin_amdgcn_update_dpp(
            (int)v, (int)v, 0xB1, 0xF, 0xF, false);   // quad_perm(1,0,3,2)
    } else if (J == 2) {
        return (unsigned)__builtin_amdgcn_update_dpp(
            (int)v, (int)v, 0x4E, 0xF, 0xF, false);   // quad_perm(2,3,0,1)
    }
    return (unsigned)__shfl_xor((int)v, J, 64);
}

template <int K, int J>
static __device__ __forceinline__ void bstep(unsigned& v, int lane) {
    const unsigned p = xpart<J>(v);
    const bool keepmin = (((lane & J) == 0) == ((lane & K) == 0));
    const unsigned mn = umin2(v, p);
    const unsigned mx = umax2(v, p);
    v = keepmin ? mn : mx;
}

// full ascending bitonic sort of 64 lanes (verified formula, R19/R20)
static __device__ __forceinline__ void bitonic64(unsigned& v, int lane) {
    bstep<2, 1>(v, lane);
    bstep<4, 2>(v, lane);  bstep<4, 1>(v, lane);
    bstep<8, 4>(v, lane);  bstep<8, 2>(v, lane);  bstep<8, 1>(v, lane);
    bstep<16, 8>(v, lane); bstep<16, 4>(v, lane); bstep<16, 2>(v, lane);
    bstep<16, 1>(v, lane);
    bstep<32, 16>(v, lane); bstep<32, 8>(v, lane); bstep<32, 4>(v, lane);
    bstep<32, 2>(v, lane);  bstep<32, 1>(v, lane);
    bstep<64, 32>(v, lane); bstep<64, 16>(v, lane); bstep<64, 8>(v, lane);
    bstep<64, 4>(v, lane);  bstep<64, 2>(v, lane);  bstep<64, 1>(v, lane);
}

__global__ __launch_bounds__(256)
void RadiusInteractionGraph_73246372266582_kernel(const float* __restrict__ pos,
                                                  float* __restrict__ out) {
    __shared__ float4 atoms[512];        // x, y, z, |p|^2
    __shared__ unsigned wbuf[4][2][64];  // per-wave, per-interleaved-row

    const int tid     = threadIdx.x;
    const int b       = blockIdx.x >> 5;          // 32 blocks per molecule
    const int rowbase = (blockIdx.x & 31) * 16;   // 16 rows per block
    const int base    = b * 512;

    for (int a = tid; a < 512; a += 256) {
        float x = pos[(base + a) * 3 + 0];
        float y = pos[(base + a) * 3 + 1];
        float z = pos[(base + a) * 3 + 2];
        // np: sum(p*p) = (x*x + y*y) + z*z, sequential f32, no fma
        float sq = __fadd_rn(__fadd_rn(__fmul_rn(x, x), __fmul_rn(y, y)),
                             __fmul_rn(z, z));
        atoms[a] = make_float4(x, y, z, sq);
    }
    __syncthreads();

    const int wave = tid >> 6;
    const int lane = tid & 63;

    for (int rp = 0; rp < 2; ++rp) {
        const int iA = rowbase + wave * 4 + rp * 2;
        const int iB = iA + 1;
        const float4 cA = atoms[iA];
        const float4 cB = atoms[iB];

        // ---- build 8 UNIQUE keys per lane for both rows (interleaved) ----
        unsigned qA[8], qB[8];
#pragma unroll
        for (int c = 0; c < 8; ++c) {
            const int j = c * 64 + lane;
            const float4 pj = atoms[j];           // one ds_read_b128, shared
            // np einsum order: ((xi*xj + yi*yj) + zi*zj), plain f32, no fma
            float dotA = __fadd_rn(__fadd_rn(__fmul_rn(cA.x, pj.x),
                                             __fmul_rn(cA.y, pj.y)),
                                   __fmul_rn(cA.z, pj.z));
            float dotB = __fadd_rn(__fadd_rn(__fmul_rn(cB.x, pj.x),
                                             __fmul_rn(cB.y, pj.y)),
                                   __fmul_rn(cB.z, pj.z));
            float d2A = __fsub_rn(__fadd_rn(cA.w, pj.w), __fmul_rn(2.0f, dotA));
            float d2B = __fsub_rn(__fadd_rn(cB.w, pj.w), __fmul_rn(2.0f, dotB));
            d2A = fmaxf(d2A, 0.0f);
            d2B = fmaxf(d2B, 0.0f);
            qA[c] = ((j != iA) && (d2A <= 100.0f))
                        ? ((__float_as_uint(d2A) & 0xFFFFFE00u) | (unsigned)j)
                        : (0x7F800000u | (unsigned)j);
            qB[c] = ((j != iB) && (d2B <= 100.0f))
                        ? ((__float_as_uint(d2B) & 0xFFFFFE00u) | (unsigned)j)
                        : (0x7F800000u | (unsigned)j);
        }

        // ---- truncated greedy MSB rank bound, interleaved (bits 30..21) ----
        unsigned XA = 0u, XB = 0u;
        for (int bit = 30; bit >= 21; --bit) {
            const unsigned CA = XA | (1u << bit);
            const unsigned CB = XB | (1u << bit);
            const unsigned ca = count_lt(qA, CA);
            const unsigned cb = count_lt(qB, CB);
            if (ca < 32u) XA = CA;
            if (cb < 32u) XB = CB;
        }
        unsigned hiA = XA + (1u << 21);
        unsigned hiB = XB + (1u << 21);
        const unsigned WA = count_lt(qA, hiA);
        const unsigned WB = count_lt(qB, hiB);
        if (WA > 64u) {   // pathological: refine exactly (R19 path)
            for (int bit = 20; bit >= 0; --bit) {
                const unsigned C = XA | (1u << bit);
                if (count_lt(qA, C) < 32u) XA = C;
            }
            hiA = XA + 1u;
        }
        if (WB > 64u) {
            for (int bit = 20; bit >= 0; --bit) {
                const unsigned C = XB | (1u << bit);
                if (count_lt(qB, C) < 32u) XB = C;
            }
            hiB = XB + 1u;
        }

        // ---- compact both windows (ballot+mbcnt), sentinel-pad to 64 ----
        wbuf[wave][0][lane] = 0xFFFFFFFFu;
        wbuf[wave][1][lane] = 0xFFFFFFFFu;
        unsigned tA = 0, tB = 0;
#pragma unroll
        for (int c = 0; c < 8; ++c) {
            const bool sA = (qA[c] < hiA);
            const bool sB = (qB[c] < hiB);
            const unsigned long long mA = __ballot(sA);
            const unsigned long long mB = __ballot(sB);
            const unsigned oA = tA + mbcnt64(mA);
            const unsigned oB = tB + mbcnt64(mB);
            if (sA) wbuf[wave][0][oA] = qA[c];
            if (sB) wbuf[wave][1][oB] = qB[c];
            tA += (unsigned)__popcll(mA);
            tB += (unsigned)__popcll(mB);
        }

        unsigned vA = wbuf[wave][0][lane];   // per-wave LDS is in-order
        unsigned vB = wbuf[wave][1][lane];

        // ---- two interleaved bitonic sort-64s (independent chains) ----
        bitonic64(vA, lane);
        bitonic64(vB, lane);

        // ---- epilogue: lanes 0..31, coalesced 128 B per region per row ----
        if (lane < 32) {
#pragma unroll
            for (int s = 0; s < 2; ++s) {
                const unsigned v = s ? vB : vA;
                const float4 ci = s ? cB : cA;
                const int gdst = base + (s ? iB : iA);
                float w = 0.0f;
                float srcf = (float)gdst;     // sentinel -> self-edge, w=0
                if (v < 0x7F800000u) {
                    const int j = (int)(v & 511u);
                    const float4 pj = atoms[j];
                    float dot = __fadd_rn(__fadd_rn(__fmul_rn(ci.x, pj.x),
                                                    __fmul_rn(ci.y, pj.y)),
                                          __fmul_rn(ci.z, pj.z));
                    float d2 = __fsub_rn(__fadd_rn(ci.w, pj.w),
                                         __fmul_rn(2.0f, dot));
                    d2 = fmaxf(d2, 0.0f);
                    w = __fsqrt_rn(fmaxf(d2, 1e-12f));
                    srcf = (float)(base + j);
                }
                const size_t eb = (size_t)gdst * 32 + (size_t)lane;
                out[eb]                     = srcf;          // src
                out[(size_t)EDGES + eb]     = (float)gdst;   // dst
                out[(size_t)EDGES * 2 + eb] = w;             // weight
            }
        }
    }
}

extern "C" void kernel_launch(void* const* d_in, const int* in_sizes, int n_in,
                              void* d_out, int out_size, void* d_ws, size_t ws_size,
                              hipStream_t stream) {
    (void)in_sizes; (void)n_in; (void)d_ws; (void)ws_size; (void)out_size;
    const float* pos = (const float*)d_in[0];   // [N,3] f32
    float* out       = (float*)d_out;           // [3E] f32

    RadiusInteractionGraph_73246372266582_kernel<<<dim3(4096), dim3(256), 0,
                                                   stream>>>(pos, out);
}
